// Round 7
// baseline (225.365 us; speedup 1.0000x reference)
//
#include <hip/hip_runtime.h>
#include <hip/hip_bf16.h>

// ---- constants for this problem ----
// N=8192 tokens, DIM=1024, H=16, HKV=4, HD=64, B=8, S=1024

typedef __bf16 bf16x8 __attribute__((ext_vector_type(8)));
typedef float f32x4 __attribute__((ext_vector_type(4)));

__device__ __forceinline__ void async16(const void* g, void* l) {
  __builtin_amdgcn_global_load_lds((const __attribute__((address_space(1))) void*)g,
                                   (__attribute__((address_space(3))) void*)l, 16, 0, 0);
}

__device__ __forceinline__ unsigned short f2bfu(float x) {
  __hip_bfloat16 h = __float2bfloat16(x);
  return __builtin_bit_cast(unsigned short, h);
}

// ---------------- all input casts in one kernel ----------------
__global__ __launch_bounds__(256) void castall(
    const float4* __restrict__ x, const float4* __restrict__ Wq,
    const float4* __restrict__ Wk, const float4* __restrict__ Wv,
    const float4* __restrict__ Wp,
    ushort4* __restrict__ xb, ushort4* __restrict__ w1b, ushort4* __restrict__ wpb) {
  int i = blockIdx.x * 256 + threadIdx.x;  // total 2752512
  const float4* src;
  ushort4* dst;
  if (i < 2097152)      { src = x + i;             dst = xb + i; }
  else if (i < 2359296) { src = Wq + (i - 2097152); dst = w1b + (i - 2097152); }
  else if (i < 2424832) { src = Wk + (i - 2359296); dst = w1b + (i - 2097152); }
  else if (i < 2490368) { src = Wv + (i - 2424832); dst = w1b + (i - 2097152); }
  else                  { src = Wp + (i - 2490368); dst = wpb + (i - 2490368); }
  float4 v = *src;
  ushort4 o;
  o.x = f2bfu(v.x); o.y = f2bfu(v.y); o.z = f2bfu(v.z); o.w = f2bfu(v.w);
  *dst = o;
}

// ---------------- fused QKV GEMM + RMSNorm + RoPE + gain -> bf16 q/k + V^T ----------------
// C = x @ [Wq;Wk;Wv]^T, tile 128x128, BK=32. Each wave's 64x64 tile is one
// head x 64 tokens; norm/rope run in-register in the epilogue. V heads write
// TRANSPOSED directly into Vt[b][kvh][d][s] (replaces the vtrans kernel).
// __launch_bounds__(256,3): pin 3 blocks/CU (epilogue would push regs to 184
// -> 2 blocks/CU otherwise; R5 measured 63us vs 49.6us).
__global__ __launch_bounds__(256, 3) void gemm_qkv(
    const __hip_bfloat16* __restrict__ A,   // [8192][1024] bf16
    const __hip_bfloat16* __restrict__ Bm,  // [1536][1024] bf16
    const float* __restrict__ cosb, const float* __restrict__ sinb,
    const float* __restrict__ qgain, const float* __restrict__ qscale,
    const float* __restrict__ kscale,
    __hip_bfloat16* __restrict__ Qo,  // [8192][16][64]
    __hip_bfloat16* __restrict__ Ko,  // [8192][4][64]
    __hip_bfloat16* __restrict__ Vt)  // [8][4][64][1024]
{
  __shared__ __align__(16) unsigned short As[128 * 32];
  __shared__ __align__(16) unsigned short Bs[128 * 32];
  const int tid = threadIdx.x;
  const int wave = tid >> 6, lane = tid & 63;
  const int quad = lane >> 4, l15 = lane & 15;
  const int bn = blockIdx.x, bm = blockIdx.y;
  const int wm = (wave >> 1) * 64, wn = (wave & 1) * 64;
  const int srow = lane >> 2, scol = (lane & 3) * 8;
  const int K = 1024;

  f32x4 acc[4][4] = {};

  const __hip_bfloat16* Ab = A + (size_t)bm * 128 * K;
  const __hip_bfloat16* Bb = Bm + (size_t)bn * 128 * K;

  for (int kt = 0; kt < K; kt += 32) {
    __syncthreads();
#pragma unroll
    for (int c = 0; c < 2; c++) {
      const int ch = wave * 2 + c;
      async16(Ab + (size_t)(ch * 16 + srow) * K + kt + scol, &As[ch * 512]);
      async16(Bb + (size_t)(ch * 16 + srow) * K + kt + scol, &Bs[ch * 512]);
    }
    __syncthreads();
    bf16x8 af[4], bfr[4];
#pragma unroll
    for (int mt = 0; mt < 4; mt++)
      af[mt] = *(const bf16x8*)&As[(wm + mt * 16 + l15) * 32 + quad * 8];
#pragma unroll
    for (int nt = 0; nt < 4; nt++)
      bfr[nt] = *(const bf16x8*)&Bs[(wn + nt * 16 + l15) * 32 + quad * 8];
#pragma unroll
    for (int mt = 0; mt < 4; mt++)
#pragma unroll
      for (int nt = 0; nt < 4; nt++)
        acc[mt][nt] = __builtin_amdgcn_mfma_f32_16x16x32_bf16(af[mt], bfr[nt], acc[mt][nt], 0, 0, 0);
  }

  // ---- fused epilogue ----
  const int hg = bn * 2 + (wn >> 6);        // global output head 0..23
  const int tokbase = bm * 128 + wm;        // wave's first token

  if (hg >= 20) {
    // V head: write transposed into Vt[b][kvh][d][s] (tok span stays in one b)
    const int hv = hg - 20;
    const int bb = tokbase >> 10;
    const int sbase = (tokbase & 1023) + quad * 4;
    unsigned short* vt = (unsigned short*)Vt;
#pragma unroll
    for (int nt = 0; nt < 4; nt++) {
      const size_t rowoff = ((size_t)((bb * 4 + hv) * 64 + nt * 16 + l15)) * 1024;
#pragma unroll
      for (int mt = 0; mt < 4; mt++) {
        ushort4 pk;
        unsigned short* pp = (unsigned short*)&pk;
#pragma unroll
        for (int r = 0; r < 4; r++) pp[r] = f2bfu(acc[mt][nt][r]);
        *(ushort4*)&vt[rowoff + sbase + mt * 16] = pk;
      }
    }
  } else {
    const bool isq = hg < 16;
    const float scale = isq ? qscale[0] : kscale[0];
    const float gain = isq ? qgain[hg] : 1.0f;  // rope is linear -> fold gain into inv
    const float sg = scale * gain;
#pragma unroll
    for (int mt = 0; mt < 4; mt++) {
      float inv[4];
#pragma unroll
      for (int r = 0; r < 4; r++) {
        float ss = acc[mt][0][r] * acc[mt][0][r] + acc[mt][1][r] * acc[mt][1][r] +
                   acc[mt][2][r] * acc[mt][2][r] + acc[mt][3][r] * acc[mt][3][r];
#pragma unroll
        for (int off = 1; off < 16; off <<= 1) ss += __shfl_xor(ss, off);
        inv[r] = rsqrtf(ss * (1.0f / 64.0f) + 1.1920929e-07f) * sg;
      }
#pragma unroll
      for (int r = 0; r < 4; r++) {
        const int tok = tokbase + mt * 16 + quad * 4 + r;
        const float c0 = cosb[tok * 32 + l15], c1 = cosb[tok * 32 + 16 + l15];
        const float s0 = sinb[tok * 32 + l15], s1 = sinb[tok * 32 + 16 + l15];
        const float v0 = acc[mt][0][r] * inv[r];
        const float v1 = acc[mt][1][r] * inv[r];
        const float v2 = acc[mt][2][r] * inv[r];
        const float v3 = acc[mt][3][r] * inv[r];
        const float o0 = v0 * c0 + v2 * s0;
        const float o1 = v1 * c1 + v3 * s1;
        const float o2 = -v0 * s0 + v2 * c0;
        const float o3 = -v1 * s1 + v3 * c1;
        __hip_bfloat16* base = isq ? (Qo + (size_t)tok * 1024 + hg * 64)
                                   : (Ko + (size_t)tok * 256 + (hg - 16) * 64);
        base[l15]      = __float2bfloat16(o0);
        base[16 + l15] = __float2bfloat16(o1);
        base[32 + l15] = __float2bfloat16(o2);
        base[48 + l15] = __float2bfloat16(o3);
      }
    }
  }
}

// ---------------- proj GEMM: out = y @ Wp^T, tile 128x64 (4 blocks/CU) ----------------
__global__ __launch_bounds__(256, 4) void gemm_p(
    const __hip_bfloat16* __restrict__ A,   // [8192][1024] bf16
    const __hip_bfloat16* __restrict__ Bm,  // [1024][1024] bf16
    float* __restrict__ C)                  // [8192][1024] f32
{
  __shared__ __align__(16) unsigned short As[128 * 32];
  __shared__ __align__(16) unsigned short Bs[64 * 32];
  const int tid = threadIdx.x;
  const int wave = tid >> 6, lane = tid & 63;
  const int quad = lane >> 4, l15 = lane & 15;
  const int bn = blockIdx.x, bm = blockIdx.y;
  const int wm = wave * 32;                 // waves stacked in M
  const int srow = lane >> 2, scol = (lane & 3) * 8;
  const int K = 1024;

  f32x4 acc[2][4] = {};

  const __hip_bfloat16* Ab = A + (size_t)bm * 128 * K;
  const __hip_bfloat16* Bb = Bm + (size_t)bn * 64 * K;

  for (int kt = 0; kt < K; kt += 32) {
    __syncthreads();
#pragma unroll
    for (int c = 0; c < 2; c++) {
      const int ch = wave * 2 + c;
      async16(Ab + (size_t)(ch * 16 + srow) * K + kt + scol, &As[ch * 512]);
    }
    async16(Bb + (size_t)(wave * 16 + srow) * K + kt + scol, &Bs[wave * 512]);
    __syncthreads();
    bf16x8 af[2], bfr[4];
#pragma unroll
    for (int mt = 0; mt < 2; mt++)
      af[mt] = *(const bf16x8*)&As[(wm + mt * 16 + l15) * 32 + quad * 8];
#pragma unroll
    for (int nt = 0; nt < 4; nt++)
      bfr[nt] = *(const bf16x8*)&Bs[(nt * 16 + l15) * 32 + quad * 8];
#pragma unroll
    for (int mt = 0; mt < 2; mt++)
#pragma unroll
      for (int nt = 0; nt < 4; nt++)
        acc[mt][nt] = __builtin_amdgcn_mfma_f32_16x16x32_bf16(af[mt], bfr[nt], acc[mt][nt], 0, 0, 0);
  }

#pragma unroll
  for (int mt = 0; mt < 2; mt++)
#pragma unroll
    for (int nt = 0; nt < 4; nt++)
#pragma unroll
      for (int r = 0; r < 4; r++) {
        const int row = bm * 128 + wm + mt * 16 + quad * 4 + r;
        const int col = bn * 64 + nt * 16 + l15;
        C[(size_t)row * 1024 + col] = acc[mt][nt][r];
      }
}

// ---------------- flash attention v4 ----------------
// Block = (qh, kvh, b): 32 q-rows x 4 heads, 4 waves (one per head).
// Grid 1024 blocks, LDS ~51KB -> 3 blocks/CU (3 independent barrier domains,
// 4-wave barriers instead of 8-wave). Static-max softmax as v3.1.
__global__ __launch_bounds__(256, 3) void attn(
    const __hip_bfloat16* __restrict__ Q,   // [N][16][64]
    const __hip_bfloat16* __restrict__ Kk,  // [N][4][64]
    const __hip_bfloat16* __restrict__ Vt,  // [8][4][64][1024]
    __hip_bfloat16* __restrict__ Y)         // [N][16][64]
{
  __shared__ __align__(16) unsigned short Kb[2][4096];  // [buf][kc*2048 + key*32 + d]
  __shared__ __align__(16) unsigned short Vb[2][4096];  // [buf][kc*2048 + d*32 + key]
  __shared__ __align__(16) unsigned short Pm[4][32 * 72];  // per-wave P[m][key]
  __shared__ float Lsh[4][32];

  const int xx = blockIdx.x;                       // 0..31
  const int qh = (xx & 1) ? (xx >> 1) : (31 - (xx >> 1));  // long blocks first
  const int kvh = blockIdx.y, b = blockIdx.z;
  const int tid = threadIdx.x;
  const int wave = tid >> 6, lane = tid & 63;
  const int quad = lane >> 4, l15 = lane & 15;
  const int h = kvh * 4 + wave;                    // one head per wave
  const int tok0 = b * 1024 + qh * 32;             // 32 q-rows per block
  const int m0 = (qh & 1) * 32;                    // q offset within diag k-tile
  const int nkt = (qh >> 1) + 1;

  const int srow = lane >> 2;
  const int scol = (lane & 3) * 8;

  // Q fragments (B-operand: l15 = q-row)
  bf16x8 qf[2][2];
#pragma unroll
  for (int mt = 0; mt < 2; mt++)
#pragma unroll
    for (int kc = 0; kc < 2; kc++)
      qf[mt][kc] = *(const bf16x8*)(Q + (size_t)(tok0 + mt * 16 + l15) * 1024 +
                                    h * 64 + kc * 32 + quad * 8);

  // issue K/V tile kt: 16 chunks of 1KB; each wave issues 4
  auto issue = [&](int kt, unsigned short* Ks, unsigned short* Vs) {
#pragma unroll
    for (int c = 0; c < 4; c++) {
      const int ch = wave * 4 + c;       // 0..15
      const int v = ch >> 3;
      const int ch8 = ch & 7;
      const int kc = ch8 >> 2, grp = ch8 & 3;
      if (v == 0)
        async16(Kk + (size_t)(b * 1024 + kt * 64 + grp * 16 + srow) * 256 + kvh * 64 + kc * 32 + scol,
                Ks + kc * 2048 + grp * 512 + lane * 8);
      else
        async16(Vt + ((size_t)((b * 4 + kvh) * 64 + grp * 16 + srow)) * 1024 + kt * 64 + kc * 32 + scol,
                Vs + kc * 2048 + grp * 512 + lane * 8);
    }
  };

  issue(0, Kb[0], Vb[0]);

  f32x4 of[2][4] = {};
  float lsum[2] = {0.0f, 0.0f};
  const float scl2 = 0.125f * 1.44269504089f;
  unsigned short* Pw = Pm[wave];

  for (int kt = 0; kt < nkt; kt++) {
    __syncthreads();
    if (kt + 1 < nkt) issue(kt + 1, Kb[(kt + 1) & 1], Vb[(kt + 1) & 1]);
    const unsigned short* Ks = Kb[kt & 1];
    const unsigned short* Vs = Vb[kt & 1];

    // S^T = K Q^T : C[key=quad*4+r (x4 kk)][m=l15 (x2 mt)]
    f32x4 sf[4][2] = {};
#pragma unroll
    for (int kc = 0; kc < 2; kc++) {
#pragma unroll
      for (int kk = 0; kk < 4; kk++) {
        const bf16x8 kf = *(const bf16x8*)&Ks[kc * 2048 + (kk * 16 + l15) * 32 + quad * 8];
#pragma unroll
        for (int mt = 0; mt < 2; mt++)
          sf[kk][mt] = __builtin_amdgcn_mfma_f32_16x16x32_bf16(kf, qf[mt][kc], sf[kk][mt], 0, 0, 0);
      }
    }

    // static-max softmax + pack P (4 consecutive keys -> one b64 store)
    const bool diag = (kt == (qh >> 1));
#pragma unroll
    for (int mt = 0; mt < 2; mt++) {
#pragma unroll
      for (int kk = 0; kk < 4; kk++) {
        ushort4 pk;
        unsigned short* pp = (unsigned short*)&pk;
#pragma unroll
        for (int r = 0; r < 4; r++) {
          float p;
          if (diag && (kk * 16 + quad * 4 + r) > (m0 + mt * 16 + l15)) {
            p = 0.0f;
          } else {
            p = __builtin_amdgcn_exp2f(sf[kk][mt][r] * scl2);
          }
          lsum[mt] += p;
          pp[r] = f2bfu(p);
        }
        *(ushort4*)&Pw[(mt * 16 + l15) * 72 + kk * 16 + quad * 4] = pk;
      }
    }

    // wave-private P: drain LDS writes only (no block barrier)
    asm volatile("s_waitcnt lgkmcnt(0)" ::: "memory");

    // O += P V : C[m=quad*4+r][d=l15]
#pragma unroll
    for (int kc = 0; kc < 2; kc++) {
#pragma unroll
      for (int mt = 0; mt < 2; mt++) {
        const bf16x8 ap = *(const bf16x8*)&Pw[(mt * 16 + l15) * 72 + kc * 32 + quad * 8];
#pragma unroll
        for (int dt = 0; dt < 4; dt++) {
          const bf16x8 bv = *(const bf16x8*)&Vs[kc * 2048 + (dt * 16 + l15) * 32 + quad * 8];
          of[mt][dt] = __builtin_amdgcn_mfma_f32_16x16x32_bf16(ap, bv, of[mt][dt], 0, 0, 0);
        }
      }
    }
  }

  // epilogue: reduce l over quads (cols were on l15), share via LDS, write O/l
#pragma unroll
  for (int mt = 0; mt < 2; mt++) {
    float l = lsum[mt];
    l += __shfl_xor(l, 16);
    l += __shfl_xor(l, 32);
    Lsh[wave][mt * 16 + l15] = l;
  }
  asm volatile("s_waitcnt lgkmcnt(0)" ::: "memory");

#pragma unroll
  for (int mt = 0; mt < 2; mt++)
#pragma unroll
    for (int r = 0; r < 4; r++) {
      const float rcp = 1.0f / Lsh[wave][mt * 16 + quad * 4 + r];
      const int row = tok0 + mt * 16 + quad * 4 + r;
#pragma unroll
      for (int dt = 0; dt < 4; dt++)
        Y[(size_t)row * 1024 + h * 64 + dt * 16 + l15] = __float2bfloat16(of[mt][dt][r] * rcp);
    }
}

// ---------------- launch ----------------
extern "C" void kernel_launch(void* const* d_in, const int* in_sizes, int n_in,
                              void* d_out, int out_size, void* d_ws, size_t ws_size,
                              hipStream_t stream) {
  const float* x      = (const float*)d_in[0];
  const float* Wq     = (const float*)d_in[1];
  const float* Wk     = (const float*)d_in[2];
  const float* Wv     = (const float*)d_in[3];
  const float* Wp     = (const float*)d_in[4];
  const float* qgain  = (const float*)d_in[5];
  const float* qscale = (const float*)d_in[6];
  const float* kscale = (const float*)d_in[7];
  const float* cosb   = (const float*)d_in[8];
  const float* sinb   = (const float*)d_in[9];
  float* out = (float*)d_out;
  char* ws = (char*)d_ws;

  __hip_bfloat16* xb  = (__hip_bfloat16*)(ws);                 // 8192x1024 bf16 @0
  __hip_bfloat16* w1b = (__hip_bfloat16*)(ws + 16777216);      // 1536x1024 bf16
  __hip_bfloat16* wpb = (__hip_bfloat16*)(ws + 19922944);      // 1024x1024 bf16
  __hip_bfloat16* qb  = (__hip_bfloat16*)(ws + 22020096);      // 8192x1024 bf16
  __hip_bfloat16* kb  = (__hip_bfloat16*)(ws + 38797312);      // 8192x256 bf16
  __hip_bfloat16* vtb = (__hip_bfloat16*)(ws + 42991616);      // 8x4x64x1024 bf16
  __hip_bfloat16* yb  = (__hip_bfloat16*)(ws + 47185920);      // 8192x1024 bf16

  castall<<<10752, 256, 0, stream>>>((const float4*)x, (const float4*)Wq, (const float4*)Wk,
                                     (const float4*)Wv, (const float4*)Wp,
                                     (ushort4*)xb, (ushort4*)w1b, (ushort4*)wpb);

  gemm_qkv<<<dim3(12, 64), 256, 0, stream>>>(xb, w1b, cosb, sinb, qgain, qscale, kscale,
                                             qb, kb, vtb);

  attn<<<dim3(32, 4, 8), 256, 0, stream>>>(qb, kb, vtb, yb);

  gemm_p<<<dim3(16, 64), 256, 0, stream>>>(yb, wpb, out);
}